// Round 1
// baseline (214.356 us; speedup 1.0000x reference)
//
#include <hip/hip_runtime.h>
#include <hip/hip_bf16.h>
#include <math.h>

#define T_TOK 3072
#define HID   1024
#define NH    16
#define HD    64

typedef __attribute__((ext_vector_type(8))) short bf16x8;
typedef __attribute__((ext_vector_type(4))) float f32x4;

static __device__ __forceinline__ unsigned short f2bf(float x) {
  __hip_bfloat16 h = __float2bfloat16(x);
  return __builtin_bit_cast(unsigned short, h);
}

// ---------------- elementwise fp32 -> bf16 ----------------
__global__ __launch_bounds__(256) void cvt_bf16(const float* __restrict__ in,
                                                unsigned short* __restrict__ out, int n) {
  int i = (blockIdx.x * 256 + threadIdx.x) * 4;
  if (i < n) {
    float4 v = *(const float4*)(in + i);
    ushort4 o;
    o.x = f2bf(v.x); o.y = f2bf(v.y); o.z = f2bf(v.z); o.w = f2bf(v.w);
    *(ushort4*)(out + i) = o;
  }
}

// ---------------- transpose + convert: out[C][R] = bf16(in[R][C]) ----------------
__global__ __launch_bounds__(256) void transpose_cvt(const float* __restrict__ in,
                                                     unsigned short* __restrict__ out,
                                                     int R, int C) {
  __shared__ float tile[32][33];
  int c0 = blockIdx.x * 32, r0 = blockIdx.y * 32;
  int tx = threadIdx.x & 31, ty = threadIdx.x >> 5; // ty 0..7
  #pragma unroll
  for (int i = 0; i < 32; i += 8)
    tile[ty + i][tx] = in[(size_t)(r0 + ty + i) * C + c0 + tx];
  __syncthreads();
  #pragma unroll
  for (int i = 0; i < 32; i += 8)
    out[(size_t)(c0 + ty + i) * R + r0 + tx] = f2bf(tile[tx][ty + i]);
}

// ---------------- RoPE cos/sin tables [T][32] ----------------
__global__ __launch_bounds__(256) void rope_table(const int* __restrict__ pos,
                                                  float* __restrict__ ctab,
                                                  float* __restrict__ stab) {
  int i = blockIdx.x * 256 + threadIdx.x;  // T*32
  int t = i >> 5, j = i & 31;
  // inv_freq[j] = 10000^(-j/32) ; ln(10000)/32 = 0.28782313662425572
  float inv = expf(-(float)j * 0.28782313662425572f);
  float f = (float)pos[t] * inv;
  ctab[i] = cosf(f);
  stab[i] = sinf(f);
}

// ---------------- RoPE apply + split Q,K to [H][T][D] bf16 ----------------
__global__ __launch_bounds__(256) void rope_split(const float* __restrict__ QKV,
                                                  const float* __restrict__ ctab,
                                                  const float* __restrict__ stab,
                                                  unsigned short* __restrict__ Qh,
                                                  unsigned short* __restrict__ Kh) {
  int i = blockIdx.x * 256 + threadIdx.x;  // T*NH*32
  int j = i & 31, h = (i >> 5) & 15, t = i >> 9;
  size_t base = (size_t)t * (3 * HID) + h * HD + j;
  float c = ctab[t * 32 + j], s = stab[t * 32 + j];
  float q1 = QKV[base], q2 = QKV[base + 32];
  float k1 = QKV[base + HID], k2 = QKV[base + HID + 32];
  size_t ob = ((size_t)h * T_TOK + t) * HD + j;
  Qh[ob]      = f2bf(q1 * c - q2 * s);
  Qh[ob + 32] = f2bf(q2 * c + q1 * s);
  Kh[ob]      = f2bf(k1 * c - k2 * s);
  Kh[ob + 32] = f2bf(k2 * c + k1 * s);
}

// ---------------- V: QKV[:,2048+h*64+d] -> Vt[H][D][T] bf16 ----------------
__global__ __launch_bounds__(256) void v_transpose(const float* __restrict__ QKV,
                                                   unsigned short* __restrict__ Vt) {
  int h = blockIdx.y;
  int t0 = blockIdx.x * 64;
  __shared__ unsigned short lds[64][72];
  int tx = threadIdx.x & 63, ty = threadIdx.x >> 6;  // ty 0..3
  #pragma unroll
  for (int i = 0; i < 16; ++i) {
    int t = ty * 16 + i;
    lds[tx][t] = f2bf(QKV[(size_t)(t0 + t) * (3 * HID) + 2 * HID + h * HD + tx]);
  }
  __syncthreads();
  #pragma unroll
  for (int i = 0; i < 16; ++i) {
    int d = ty * 16 + i;
    Vt[((size_t)h * HD + d) * T_TOK + t0 + tx] = lds[d][tx];
  }
}

// ---------------- GEMM: C[M,N] f32 = A[M,K] bf16 x Bt[N,K] bf16 ----------------
// 128x128 tile, BK=64, 4 waves (2x2), global_load_lds staging, 16x16x32 MFMA
__global__ __launch_bounds__(256) void gemm_bt(const unsigned short* __restrict__ A,
                                               const unsigned short* __restrict__ Bt,
                                               float* __restrict__ C,
                                               int M, int N, int K) {
  __shared__ unsigned short As[128 * 64];
  __shared__ unsigned short Bs[128 * 64];
  const int lane = threadIdx.x & 63;
  const int wv = threadIdx.x >> 6;
  const int wm = wv >> 1, wn = wv & 1;
  const int r = lane & 15, hi = lane >> 4;
  const int m0 = blockIdx.y * 128, n0 = blockIdx.x * 128;
  f32x4 acc[4][4] = {};
  for (int kt = 0; kt < K; kt += 64) {
    __syncthreads();
    #pragma unroll
    for (int i = 0; i < 4; ++i) {
      int o = (wv * 4 + i) * 1024 + lane * 16;  // byte offset into 16KB tile
      int row = o >> 7;                          // 128B per row (64 bf16)
      int col = (o & 127) >> 1;
      const unsigned short* ga = A + (size_t)(m0 + row) * K + kt + col;
      __builtin_amdgcn_global_load_lds(
          (const __attribute__((address_space(1))) unsigned int*)ga,
          (__attribute__((address_space(3))) unsigned int*)((char*)As + (wv * 4 + i) * 1024),
          16, 0, 0);
      const unsigned short* gb = Bt + (size_t)(n0 + row) * K + kt + col;
      __builtin_amdgcn_global_load_lds(
          (const __attribute__((address_space(1))) unsigned int*)gb,
          (__attribute__((address_space(3))) unsigned int*)((char*)Bs + (wv * 4 + i) * 1024),
          16, 0, 0);
    }
    __syncthreads();
    #pragma unroll
    for (int kk = 0; kk < 2; ++kk) {
      bf16x8 a[4], b[4];
      #pragma unroll
      for (int tm = 0; tm < 4; ++tm)
        a[tm] = *(const bf16x8*)&As[(wm * 64 + tm * 16 + r) * 64 + kk * 32 + hi * 8];
      #pragma unroll
      for (int tn = 0; tn < 4; ++tn)
        b[tn] = *(const bf16x8*)&Bs[(wn * 64 + tn * 16 + r) * 64 + kk * 32 + hi * 8];
      #pragma unroll
      for (int tm = 0; tm < 4; ++tm)
        #pragma unroll
        for (int tn = 0; tn < 4; ++tn)
          acc[tm][tn] = __builtin_amdgcn_mfma_f32_16x16x32_bf16(a[tm], b[tn], acc[tm][tn], 0, 0, 0);
    }
  }
  #pragma unroll
  for (int tm = 0; tm < 4; ++tm)
    #pragma unroll
    for (int tn = 0; tn < 4; ++tn) {
      int colg = n0 + wn * 64 + tn * 16 + r;
      int rowg = m0 + wm * 64 + tm * 16 + hi * 4;
      float* cp = C + (size_t)rowg * N + colg;
      #pragma unroll
      for (int j = 0; j < 4; ++j) cp[(size_t)j * N] = acc[tm][tn][j];
    }
}

// ---------------- flash attention ----------------
// grid (T/64, H); block 256 = 4 waves x 16 q-rows. KVBLK=64.
// Computes S^T = mfma(K, Q) so each lane owns one q-row slice (softmax = 4-lane shfl reduce).
__global__ __launch_bounds__(256) void flash_attn(const unsigned short* __restrict__ Qh,
                                                  const unsigned short* __restrict__ Kh,
                                                  const unsigned short* __restrict__ Vt,
                                                  const float* __restrict__ mask,
                                                  unsigned short* __restrict__ Ob) {
  const int h = blockIdx.y;
  const int q0 = blockIdx.x * 64;
  __shared__ unsigned short Ks[64 * 72];
  __shared__ unsigned short Vs[64 * 72];
  __shared__ unsigned short Pl[4][16 * 72];
  const int lane = threadIdx.x & 63, wv = threadIdx.x >> 6;
  const int r = lane & 15, hi = lane >> 4;
  const int qrow = q0 + wv * 16 + r;
  const bf16x8 qf0 = *(const bf16x8*)(Qh + ((size_t)h * T_TOK + qrow) * HD + hi * 8);
  const bf16x8 qf1 = *(const bf16x8*)(Qh + ((size_t)h * T_TOK + qrow) * HD + 32 + hi * 8);
  f32x4 acc_o[4] = {};
  float m = -INFINITY, l = 0.f;
  const int strow = threadIdx.x >> 2, stc = (threadIdx.x & 3) * 16;
  const unsigned short* kg = Kh + ((size_t)h * T_TOK + strow) * HD + stc;
  const unsigned short* vg = Vt + ((size_t)h * HD + strow) * T_TOK + stc;
  const float* mrow = mask + (size_t)qrow * T_TOK;

  for (int s0 = 0; s0 < T_TOK; s0 += 64) {
    __syncthreads();
    {  // stage K tile [64 kv][64 d] and Vt tile [64 d][64 kv] into padded LDS
      float4 k0 = *(const float4*)(kg + (size_t)s0 * HD);
      float4 k1 = *(const float4*)(kg + (size_t)s0 * HD + 8);
      float4 v0 = *(const float4*)(vg + s0);
      float4 v1 = *(const float4*)(vg + s0 + 8);
      *(float4*)&Ks[strow * 72 + stc]     = k0;
      *(float4*)&Ks[strow * 72 + stc + 8] = k1;
      *(float4*)&Vs[strow * 72 + stc]     = v0;
      *(float4*)&Vs[strow * 72 + stc + 8] = v1;
    }
    __syncthreads();

    // S^T[kv, q] in 4 accs of 16 kv each
    f32x4 st[4];
    #pragma unroll
    for (int b = 0; b < 4; ++b) {
      bf16x8 kf0 = *(const bf16x8*)&Ks[(b * 16 + r) * 72 + hi * 8];
      bf16x8 kf1 = *(const bf16x8*)&Ks[(b * 16 + r) * 72 + 32 + hi * 8];
      f32x4 z = {};
      z = __builtin_amdgcn_mfma_f32_16x16x32_bf16(kf0, qf0, z, 0, 0, 0);
      z = __builtin_amdgcn_mfma_f32_16x16x32_bf16(kf1, qf1, z, 0, 0, 0);
      st[b] = z;
    }

    // scale + mask + online softmax (lane owns q = r; kv spread over hi-group)
    float sv[16];
    float pmax = -INFINITY;
    #pragma unroll
    for (int b = 0; b < 4; ++b) {
      float4 mk = *(const float4*)(mrow + s0 + b * 16 + hi * 4);
      float mkv[4] = {mk.x, mk.y, mk.z, mk.w};
      #pragma unroll
      for (int j = 0; j < 4; ++j) {
        float v = st[b][j] * 0.125f + mkv[j];
        sv[b * 4 + j] = v;
        pmax = fmaxf(pmax, v);
      }
    }
    pmax = fmaxf(pmax, __shfl_xor(pmax, 16));
    pmax = fmaxf(pmax, __shfl_xor(pmax, 32));
    float mnew = fmaxf(m, pmax);
    float sc = __expf(m - mnew);
    float ps = 0.f;
    unsigned short pb[16];
    #pragma unroll
    for (int i = 0; i < 16; ++i) {
      float p = __expf(sv[i] - mnew);
      ps += p;
      pb[i] = f2bf(p);
    }
    ps += __shfl_xor(ps, 16);
    ps += __shfl_xor(ps, 32);
    l = l * sc + ps;
    m = mnew;

    // write P (bf16) to wave-private LDS in A-operand layout: Pl[q][kv]
    #pragma unroll
    for (int b = 0; b < 4; ++b) {
      unsigned int lo  = (unsigned int)pb[b * 4]     | ((unsigned int)pb[b * 4 + 1] << 16);
      unsigned int hi2 = (unsigned int)pb[b * 4 + 2] | ((unsigned int)pb[b * 4 + 3] << 16);
      uint2 u; u.x = lo; u.y = hi2;
      *(uint2*)&Pl[wv][r * 72 + b * 16 + hi * 4] = u;
    }

    // rescale O rows (lane owns O rows q = hi*4+j -> fetch their scale from lane q)
    float sc0 = __shfl(sc, hi * 4 + 0);
    float sc1 = __shfl(sc, hi * 4 + 1);
    float sc2 = __shfl(sc, hi * 4 + 2);
    float sc3 = __shfl(sc, hi * 4 + 3);
    #pragma unroll
    for (int d = 0; d < 4; ++d) {
      acc_o[d][0] *= sc0; acc_o[d][1] *= sc1;
      acc_o[d][2] *= sc2; acc_o[d][3] *= sc3;
    }

    // PV: O[q,d] += P[q,kv] * V[kv,d]
    bf16x8 pa0 = *(const bf16x8*)&Pl[wv][r * 72 + hi * 8];
    bf16x8 pa1 = *(const bf16x8*)&Pl[wv][r * 72 + 32 + hi * 8];
    #pragma unroll
    for (int d = 0; d < 4; ++d) {
      bf16x8 vf0 = *(const bf16x8*)&Vs[(d * 16 + r) * 72 + hi * 8];
      bf16x8 vf1 = *(const bf16x8*)&Vs[(d * 16 + r) * 72 + 32 + hi * 8];
      acc_o[d] = __builtin_amdgcn_mfma_f32_16x16x32_bf16(pa0, vf0, acc_o[d], 0, 0, 0);
      acc_o[d] = __builtin_amdgcn_mfma_f32_16x16x32_bf16(pa1, vf1, acc_o[d], 0, 0, 0);
    }
  }

  // epilogue: divide by l, store bf16 to Ob[T][HID]
  float li[4];
  #pragma unroll
  for (int j = 0; j < 4; ++j) li[j] = 1.f / __shfl(l, hi * 4 + j);
  #pragma unroll
  for (int d = 0; d < 4; ++d)
    #pragma unroll
    for (int j = 0; j < 4; ++j) {
      int trow = q0 + wv * 16 + hi * 4 + j;
      Ob[(size_t)trow * HID + h * HD + d * 16 + r] = f2bf(acc_o[d][j] * li[j]);
    }
}

extern "C" void kernel_launch(void* const* d_in, const int* in_sizes, int n_in,
                              void* d_out, int out_size, void* d_ws, size_t ws_size,
                              hipStream_t stream) {
  const float* X    = (const float*)d_in[0];
  const float* Wqkv = (const float*)d_in[1];
  const float* Wo   = (const float*)d_in[2];
  const float* mask = (const float*)d_in[3];
  const int*   pos  = (const int*)d_in[4];
  float* out = (float*)d_out;

  char* ws = (char*)d_ws;
  size_t off = 0;
  auto alloc = [&](size_t bytes) {
    char* p = ws + off;
    off += (bytes + 255) & ~(size_t)255;
    return p;
  };
  // total ~75 MB
  unsigned short* Xb    = (unsigned short*)alloc((size_t)T_TOK * HID * 2);
  unsigned short* WqkvT = (unsigned short*)alloc((size_t)3 * HID * HID * 2);
  unsigned short* WoT   = (unsigned short*)alloc((size_t)HID * HID * 2);
  float*          QKV   = (float*)alloc((size_t)T_TOK * 3 * HID * 4);
  unsigned short* Qh    = (unsigned short*)alloc((size_t)NH * T_TOK * HD * 2);
  unsigned short* Kh    = (unsigned short*)alloc((size_t)NH * T_TOK * HD * 2);
  unsigned short* Vt    = (unsigned short*)alloc((size_t)NH * HD * T_TOK * 2);
  unsigned short* Ob    = (unsigned short*)alloc((size_t)T_TOK * HID * 2);
  float*          ctab  = (float*)alloc((size_t)T_TOK * 32 * 4);
  float*          stab  = (float*)alloc((size_t)T_TOK * 32 * 4);

  cvt_bf16<<<(T_TOK * HID / 4 + 255) / 256, 256, 0, stream>>>(X, Xb, T_TOK * HID);
  transpose_cvt<<<dim3(3 * HID / 32, HID / 32), 256, 0, stream>>>(Wqkv, WqkvT, HID, 3 * HID);
  transpose_cvt<<<dim3(HID / 32, HID / 32), 256, 0, stream>>>(Wo, WoT, HID, HID);
  rope_table<<<T_TOK * 32 / 256, 256, 0, stream>>>(pos, ctab, stab);

  gemm_bt<<<dim3(3 * HID / 128, T_TOK / 128), 256, 0, stream>>>(Xb, WqkvT, QKV, T_TOK, 3 * HID, HID);

  rope_split<<<T_TOK * NH * 32 / 256, 256, 0, stream>>>(QKV, ctab, stab, Qh, Kh);
  v_transpose<<<dim3(T_TOK / 64, NH), 256, 0, stream>>>(QKV, Vt);

  flash_attn<<<dim3(T_TOK / 64, NH), 256, 0, stream>>>(Qh, Kh, Vt, mask, Ob);

  gemm_bt<<<dim3(HID / 128, T_TOK / 128), 256, 0, stream>>>(Ob, WoT, out, T_TOK, HID, HID);
}

// Round 2
// 208.309 us; speedup vs baseline: 1.0290x; 1.0290x over previous
//
#include <hip/hip_runtime.h>
#include <hip/hip_bf16.h>
#include <math.h>

#define T_TOK 3072
#define HID   1024
#define NH    16
#define HD    64
#define KVSPLIT 4
#define KVCHUNK (T_TOK / KVSPLIT)   // 768

typedef __attribute__((ext_vector_type(8))) short bf16x8;
typedef __attribute__((ext_vector_type(4))) float f32x4;

static __device__ __forceinline__ unsigned short f2bf(float x) {
  __hip_bfloat16 h = __float2bfloat16(x);
  return __builtin_bit_cast(unsigned short, h);
}

// swizzled LDS short-index for a [rows][64 bf16] tile, row stride 128B.
// byte address = row*128 + (col_bytes ^ ((row&7)<<4)); identical on write & read.
static __device__ __forceinline__ int swz(int row, int cb) {
  return row * 64 + ((cb ^ ((row & 7) << 4)) >> 1);
}

// ---------------- elementwise fp32 -> bf16 ----------------
__global__ __launch_bounds__(256) void cvt_bf16(const float* __restrict__ in,
                                                unsigned short* __restrict__ out, int n) {
  int i = (blockIdx.x * 256 + threadIdx.x) * 4;
  if (i < n) {
    float4 v = *(const float4*)(in + i);
    ushort4 o;
    o.x = f2bf(v.x); o.y = f2bf(v.y); o.z = f2bf(v.z); o.w = f2bf(v.w);
    *(ushort4*)(out + i) = o;
  }
}

// ---------------- transpose + convert: out[C][R] = bf16(in[R][C]) ----------------
__global__ __launch_bounds__(256) void transpose_cvt(const float* __restrict__ in,
                                                     unsigned short* __restrict__ out,
                                                     int R, int C) {
  __shared__ float tile[32][33];
  int c0 = blockIdx.x * 32, r0 = blockIdx.y * 32;
  int tx = threadIdx.x & 31, ty = threadIdx.x >> 5; // ty 0..7
  #pragma unroll
  for (int i = 0; i < 32; i += 8)
    tile[ty + i][tx] = in[(size_t)(r0 + ty + i) * C + c0 + tx];
  __syncthreads();
  #pragma unroll
  for (int i = 0; i < 32; i += 8)
    out[(size_t)(c0 + ty + i) * R + r0 + tx] = f2bf(tile[tx][ty + i]);
}

// ---------------- RoPE cos/sin tables [T][32] ----------------
__global__ __launch_bounds__(256) void rope_table(const int* __restrict__ pos,
                                                  float* __restrict__ ctab,
                                                  float* __restrict__ stab) {
  int i = blockIdx.x * 256 + threadIdx.x;  // T*32
  int t = i >> 5, j = i & 31;
  float inv = expf(-(float)j * 0.28782313662425572f);  // 10000^(-j/32)
  float f = (float)pos[t] * inv;
  ctab[i] = cosf(f);
  stab[i] = sinf(f);
}

// ---------------- RoPE apply + split Q,K to [H][T][D] bf16 ----------------
__global__ __launch_bounds__(256) void rope_split(const float* __restrict__ QKV,
                                                  const float* __restrict__ ctab,
                                                  const float* __restrict__ stab,
                                                  unsigned short* __restrict__ Qh,
                                                  unsigned short* __restrict__ Kh) {
  int i = blockIdx.x * 256 + threadIdx.x;  // T*NH*32
  int j = i & 31, h = (i >> 5) & 15, t = i >> 9;
  size_t base = (size_t)t * (3 * HID) + h * HD + j;
  float c = ctab[t * 32 + j], s = stab[t * 32 + j];
  float q1 = QKV[base], q2 = QKV[base + 32];
  float k1 = QKV[base + HID], k2 = QKV[base + HID + 32];
  size_t ob = ((size_t)h * T_TOK + t) * HD + j;
  Qh[ob]      = f2bf(q1 * c - q2 * s);
  Qh[ob + 32] = f2bf(q2 * c + q1 * s);
  Kh[ob]      = f2bf(k1 * c - k2 * s);
  Kh[ob + 32] = f2bf(k2 * c + k1 * s);
}

// ---------------- V: QKV[:,2048+h*64+d] -> Vt[H][D][T] bf16 ----------------
__global__ __launch_bounds__(256) void v_transpose(const float* __restrict__ QKV,
                                                   unsigned short* __restrict__ Vt) {
  int h = blockIdx.y;
  int t0 = blockIdx.x * 64;
  __shared__ unsigned short lds[64][72];
  int tx = threadIdx.x & 63, ty = threadIdx.x >> 6;  // ty 0..3
  #pragma unroll
  for (int i = 0; i < 16; ++i) {
    int t = ty * 16 + i;
    lds[tx][t] = f2bf(QKV[(size_t)(t0 + t) * (3 * HID) + 2 * HID + h * HD + tx]);
  }
  __syncthreads();
  #pragma unroll
  for (int i = 0; i < 16; ++i) {
    int d = ty * 16 + i;
    Vt[((size_t)h * HD + d) * T_TOK + t0 + tx] = lds[d][tx];
  }
}

// ---------------- GEMM: C[M,N] f32 = A[M,K] bf16 x Bt[N,K] bf16 ----------------
__global__ __launch_bounds__(256) void gemm_bt(const unsigned short* __restrict__ A,
                                               const unsigned short* __restrict__ Bt,
                                               float* __restrict__ C,
                                               int M, int N, int K) {
  __shared__ unsigned short As[128 * 64];
  __shared__ unsigned short Bs[128 * 64];
  const int lane = threadIdx.x & 63;
  const int wv = threadIdx.x >> 6;
  const int wm = wv >> 1, wn = wv & 1;
  const int r = lane & 15, hi = lane >> 4;
  const int m0 = blockIdx.y * 128, n0 = blockIdx.x * 128;
  f32x4 acc[4][4] = {};
  for (int kt = 0; kt < K; kt += 64) {
    __syncthreads();
    #pragma unroll
    for (int i = 0; i < 4; ++i) {
      int o = (wv * 4 + i) * 1024 + lane * 16;  // byte offset into 16KB tile
      int row = o >> 7;                          // 128B per row (64 bf16)
      int col = (o & 127) >> 1;
      const unsigned short* ga = A + (size_t)(m0 + row) * K + kt + col;
      __builtin_amdgcn_global_load_lds(
          (const __attribute__((address_space(1))) unsigned int*)ga,
          (__attribute__((address_space(3))) unsigned int*)((char*)As + (wv * 4 + i) * 1024),
          16, 0, 0);
      const unsigned short* gb = Bt + (size_t)(n0 + row) * K + kt + col;
      __builtin_amdgcn_global_load_lds(
          (const __attribute__((address_space(1))) unsigned int*)gb,
          (__attribute__((address_space(3))) unsigned int*)((char*)Bs + (wv * 4 + i) * 1024),
          16, 0, 0);
    }
    __syncthreads();
    #pragma unroll
    for (int kk = 0; kk < 2; ++kk) {
      bf16x8 a[4], b[4];
      #pragma unroll
      for (int tm = 0; tm < 4; ++tm)
        a[tm] = *(const bf16x8*)&As[(wm * 64 + tm * 16 + r) * 64 + kk * 32 + hi * 8];
      #pragma unroll
      for (int tn = 0; tn < 4; ++tn)
        b[tn] = *(const bf16x8*)&Bs[(wn * 64 + tn * 16 + r) * 64 + kk * 32 + hi * 8];
      #pragma unroll
      for (int tm = 0; tm < 4; ++tm)
        #pragma unroll
        for (int tn = 0; tn < 4; ++tn)
          acc[tm][tn] = __builtin_amdgcn_mfma_f32_16x16x32_bf16(a[tm], b[tn], acc[tm][tn], 0, 0, 0);
    }
  }
  #pragma unroll
  for (int tm = 0; tm < 4; ++tm)
    #pragma unroll
    for (int tn = 0; tn < 4; ++tn) {
      int colg = n0 + wn * 64 + tn * 16 + r;
      int rowg = m0 + wm * 64 + tm * 16 + hi * 4;
      float* cp = C + (size_t)rowg * N + colg;
      #pragma unroll
      for (int j = 0; j < 4; ++j) cp[(size_t)j * N] = acc[tm][tn][j];
    }
}

// ---------------- flash attention, KV-split ----------------
// grid (T/64, H, KVSPLIT); block 256 = 4 waves x 16 q-rows. KVBLK=64.
// Each block processes KVCHUNK kv positions, writes unnormalized O + (m,l).
__global__ __launch_bounds__(256) void flash_attn(const unsigned short* __restrict__ Qh,
                                                  const unsigned short* __restrict__ Kh,
                                                  const unsigned short* __restrict__ Vt,
                                                  const float* __restrict__ mask,
                                                  float* __restrict__ Op,
                                                  float* __restrict__ Mp,
                                                  float* __restrict__ Lp) {
  const int h = blockIdx.y;
  const int q0 = blockIdx.x * 64;
  const int z = blockIdx.z;
  const int kv0 = z * KVCHUNK;
  __shared__ unsigned short Ks[64 * 64];
  __shared__ unsigned short Vs[64 * 64];
  __shared__ unsigned short Pl[4][16 * 64];
  const int lane = threadIdx.x & 63, wv = threadIdx.x >> 6;
  const int r = lane & 15, hi = lane >> 4;
  const int qrow = q0 + wv * 16 + r;
  const bf16x8 qf0 = *(const bf16x8*)(Qh + ((size_t)h * T_TOK + qrow) * HD + hi * 8);
  const bf16x8 qf1 = *(const bf16x8*)(Qh + ((size_t)h * T_TOK + qrow) * HD + 32 + hi * 8);
  f32x4 acc_o[4] = {};
  float m = -INFINITY, l = 0.f;
  const int strow = threadIdx.x >> 2;            // 0..63
  const int scb = (threadIdx.x & 3) * 32;        // byte col 0/32/64/96
  const unsigned short* kg = Kh + ((size_t)h * T_TOK + strow) * HD + (scb >> 1);
  const unsigned short* vg = Vt + ((size_t)h * HD + strow) * T_TOK + (scb >> 1);
  const float* mrow = mask + (size_t)qrow * T_TOK;

  for (int s0 = kv0; s0 < kv0 + KVCHUNK; s0 += 64) {
    // prefetch mask into registers (latency hides under staging + QK^T)
    float4 mk[4];
    #pragma unroll
    for (int b = 0; b < 4; ++b) mk[b] = *(const float4*)(mrow + s0 + b * 16 + hi * 4);

    __syncthreads();
    {  // stage K [64 kv][64 d] and Vt [64 d][64 kv] into swizzled LDS
      float4 k0 = *(const float4*)(kg + (size_t)s0 * HD);
      float4 k1 = *(const float4*)(kg + (size_t)s0 * HD + 8);
      float4 v0 = *(const float4*)(vg + s0);
      float4 v1 = *(const float4*)(vg + s0 + 8);
      *(float4*)&Ks[swz(strow, scb)]      = k0;
      *(float4*)&Ks[swz(strow, scb + 16)] = k1;
      *(float4*)&Vs[swz(strow, scb)]      = v0;
      *(float4*)&Vs[swz(strow, scb + 16)] = v1;
    }
    __syncthreads();

    // S^T[kv, q]: 4 accs of 16 kv each
    f32x4 st[4];
    #pragma unroll
    for (int b = 0; b < 4; ++b) {
      bf16x8 kf0 = *(const bf16x8*)&Ks[swz(b * 16 + r, hi * 16)];
      bf16x8 kf1 = *(const bf16x8*)&Ks[swz(b * 16 + r, 64 + hi * 16)];
      f32x4 zf = {};
      zf = __builtin_amdgcn_mfma_f32_16x16x32_bf16(kf0, qf0, zf, 0, 0, 0);
      zf = __builtin_amdgcn_mfma_f32_16x16x32_bf16(kf1, qf1, zf, 0, 0, 0);
      st[b] = zf;
    }

    // scale + mask + online softmax (lane owns q-row r; kv spread over hi)
    float sv[16];
    float pmax = -INFINITY;
    #pragma unroll
    for (int b = 0; b < 4; ++b) {
      float mkv[4] = {mk[b].x, mk[b].y, mk[b].z, mk[b].w};
      #pragma unroll
      for (int j = 0; j < 4; ++j) {
        float v = st[b][j] * 0.125f + mkv[j];
        sv[b * 4 + j] = v;
        pmax = fmaxf(pmax, v);
      }
    }
    pmax = fmaxf(pmax, __shfl_xor(pmax, 16));
    pmax = fmaxf(pmax, __shfl_xor(pmax, 32));
    float mnew = fmaxf(m, pmax);
    float sc = __expf(m - mnew);
    float ps = 0.f;
    unsigned short pb[16];
    #pragma unroll
    for (int i = 0; i < 16; ++i) {
      float p = __expf(sv[i] - mnew);
      ps += p;
      pb[i] = f2bf(p);
    }
    ps += __shfl_xor(ps, 16);
    ps += __shfl_xor(ps, 32);
    l = l * sc + ps;
    m = mnew;

    // write P (bf16) to wave-private swizzled LDS: Pl[q][kv]
    #pragma unroll
    for (int b = 0; b < 4; ++b) {
      unsigned int lo  = (unsigned int)pb[b * 4]     | ((unsigned int)pb[b * 4 + 1] << 16);
      unsigned int hi2 = (unsigned int)pb[b * 4 + 2] | ((unsigned int)pb[b * 4 + 3] << 16);
      uint2 u; u.x = lo; u.y = hi2;
      *(uint2*)&Pl[wv][swz(r, b * 32 + hi * 8)] = u;
    }

    // rescale O rows (lane owns O rows q = hi*4+j)
    float sc0 = __shfl(sc, hi * 4 + 0);
    float sc1 = __shfl(sc, hi * 4 + 1);
    float sc2 = __shfl(sc, hi * 4 + 2);
    float sc3 = __shfl(sc, hi * 4 + 3);
    #pragma unroll
    for (int d = 0; d < 4; ++d) {
      acc_o[d][0] *= sc0; acc_o[d][1] *= sc1;
      acc_o[d][2] *= sc2; acc_o[d][3] *= sc3;
    }

    // PV: O[q,d] += P[q,kv] * V[kv,d]
    bf16x8 pa0 = *(const bf16x8*)&Pl[wv][swz(r, hi * 16)];
    bf16x8 pa1 = *(const bf16x8*)&Pl[wv][swz(r, 64 + hi * 16)];
    #pragma unroll
    for (int d = 0; d < 4; ++d) {
      bf16x8 vf0 = *(const bf16x8*)&Vs[swz(d * 16 + r, hi * 16)];
      bf16x8 vf1 = *(const bf16x8*)&Vs[swz(d * 16 + r, 64 + hi * 16)];
      acc_o[d] = __builtin_amdgcn_mfma_f32_16x16x32_bf16(pa0, vf0, acc_o[d], 0, 0, 0);
      acc_o[d] = __builtin_amdgcn_mfma_f32_16x16x32_bf16(pa1, vf1, acc_o[d], 0, 0, 0);
    }
  }

  // epilogue: write unnormalized partials + (m,l)
  #pragma unroll
  for (int d = 0; d < 4; ++d)
    #pragma unroll
    for (int j = 0; j < 4; ++j) {
      int trow = q0 + wv * 16 + hi * 4 + j;
      Op[(((size_t)z * T_TOK + trow) * NH + h) * HD + d * 16 + r] = acc_o[d][j];
    }
  if (hi == 0) {
    size_t mi = ((size_t)z * T_TOK + qrow) * NH + h;
    Mp[mi] = m;
    Lp[mi] = l;
  }
}

// ---------------- combine KV-split partials ----------------
__global__ __launch_bounds__(256) void combine(const float* __restrict__ Op,
                                               const float* __restrict__ Mp,
                                               const float* __restrict__ Lp,
                                               unsigned short* __restrict__ Ob) {
  int idx = blockIdx.x * 256 + threadIdx.x;  // T*256 total (4 floats each)
  int t = idx >> 8;
  int q4 = (idx & 255) * 4;  // within [HID): h*64 + d
  int h = q4 >> 6, d = q4 & 63;
  float mz[KVSPLIT], lz[KVSPLIT];
  float ms = -INFINITY;
  #pragma unroll
  for (int zz = 0; zz < KVSPLIT; ++zz) {
    size_t mi = ((size_t)zz * T_TOK + t) * NH + h;
    mz[zz] = Mp[mi];
    lz[zz] = Lp[mi];
    ms = fmaxf(ms, mz[zz]);
  }
  float lsum = 0.f;
  float w[KVSPLIT];
  #pragma unroll
  for (int zz = 0; zz < KVSPLIT; ++zz) {
    w[zz] = __expf(mz[zz] - ms);
    lsum += lz[zz] * w[zz];
  }
  float4 o = {0.f, 0.f, 0.f, 0.f};
  #pragma unroll
  for (int zz = 0; zz < KVSPLIT; ++zz) {
    float4 p = *(const float4*)(Op + (((size_t)zz * T_TOK + t) * NH + h) * HD + d);
    o.x += p.x * w[zz]; o.y += p.y * w[zz];
    o.z += p.z * w[zz]; o.w += p.w * w[zz];
  }
  float inv = 1.f / lsum;
  ushort4 ob;
  ob.x = f2bf(o.x * inv); ob.y = f2bf(o.y * inv);
  ob.z = f2bf(o.z * inv); ob.w = f2bf(o.w * inv);
  *(ushort4*)(Ob + (size_t)t * HID + q4) = ob;
}

extern "C" void kernel_launch(void* const* d_in, const int* in_sizes, int n_in,
                              void* d_out, int out_size, void* d_ws, size_t ws_size,
                              hipStream_t stream) {
  const float* X    = (const float*)d_in[0];
  const float* Wqkv = (const float*)d_in[1];
  const float* Wo   = (const float*)d_in[2];
  const float* mask = (const float*)d_in[3];
  const int*   pos  = (const int*)d_in[4];
  float* out = (float*)d_out;

  char* ws = (char*)d_ws;
  size_t off = 0;
  auto alloc = [&](size_t bytes) {
    char* p = ws + off;
    off += (bytes + 255) & ~(size_t)255;
    return p;
  };
  unsigned short* Xb    = (unsigned short*)alloc((size_t)T_TOK * HID * 2);
  unsigned short* WqkvT = (unsigned short*)alloc((size_t)3 * HID * HID * 2);
  unsigned short* WoT   = (unsigned short*)alloc((size_t)HID * HID * 2);
  unsigned short* Qh    = (unsigned short*)alloc((size_t)NH * T_TOK * HD * 2);
  unsigned short* Kh    = (unsigned short*)alloc((size_t)NH * T_TOK * HD * 2);
  unsigned short* Vt    = (unsigned short*)alloc((size_t)NH * HD * T_TOK * 2);
  unsigned short* Ob    = (unsigned short*)alloc((size_t)T_TOK * HID * 2);
  float*          ctab  = (float*)alloc((size_t)T_TOK * 32 * 4);
  float*          stab  = (float*)alloc((size_t)T_TOK * 32 * 4);
  float*          Mp    = (float*)alloc((size_t)KVSPLIT * T_TOK * NH * 4);
  float*          Lp    = (float*)alloc((size_t)KVSPLIT * T_TOK * NH * 4);
  // REGION: QKV (f32 T x 3H = 37.75MB) aliased with Opart (f32 KVSPLIT x T x HID = 50.3MB).
  // QKV is dead once rope_split + v_transpose complete, before flash_attn writes Op.
  float*          QKV   = (float*)alloc((size_t)KVSPLIT * T_TOK * HID * 4);
  float*          Op    = QKV;

  cvt_bf16<<<(T_TOK * HID / 4 + 255) / 256, 256, 0, stream>>>(X, Xb, T_TOK * HID);
  transpose_cvt<<<dim3(3 * HID / 32, HID / 32), 256, 0, stream>>>(Wqkv, WqkvT, HID, 3 * HID);
  transpose_cvt<<<dim3(HID / 32, HID / 32), 256, 0, stream>>>(Wo, WoT, HID, HID);
  rope_table<<<T_TOK * 32 / 256, 256, 0, stream>>>(pos, ctab, stab);

  gemm_bt<<<dim3(3 * HID / 128, T_TOK / 128), 256, 0, stream>>>(Xb, WqkvT, QKV, T_TOK, 3 * HID, HID);

  rope_split<<<T_TOK * NH * 32 / 256, 256, 0, stream>>>(QKV, ctab, stab, Qh, Kh);
  v_transpose<<<dim3(T_TOK / 64, NH), 256, 0, stream>>>(QKV, Vt);

  flash_attn<<<dim3(T_TOK / 64, NH, KVSPLIT), 256, 0, stream>>>(Qh, Kh, Vt, mask, Op, Mp, Lp);
  combine<<<T_TOK, 256, 0, stream>>>(Op, Mp, Lp, Ob);

  gemm_bt<<<dim3(HID / 128, T_TOK / 128), 256, 0, stream>>>(Ob, WoT, out, T_TOK, HID, HID);
}

// Round 3
// 204.466 us; speedup vs baseline: 1.0484x; 1.0188x over previous
//
#include <hip/hip_runtime.h>
#include <hip/hip_bf16.h>
#include <math.h>

#define T_TOK 3072
#define HID   1024
#define NH    16
#define HD    64
#define KVSPLIT 4
#define KVCHUNK (T_TOK / KVSPLIT)   // 768
#define LOG2E 1.4426950408889634f

typedef __attribute__((ext_vector_type(8))) short bf16x8;
typedef __attribute__((ext_vector_type(4))) short bf16x4;
typedef __attribute__((ext_vector_type(4))) float f32x4;

static __device__ __forceinline__ unsigned short f2bf(float x) {
  __hip_bfloat16 h = __float2bfloat16(x);
  return __builtin_bit_cast(unsigned short, h);
}

// swizzled LDS short-index for a [rows][64 bf16] tile, row stride 128B.
// byte address = row*128 + (col_bytes ^ ((row&7)<<4)); identical on write & read.
static __device__ __forceinline__ int swz(int row, int cb) {
  return row * 64 + ((cb ^ ((row & 7) << 4)) >> 1);
}

// ---------------- elementwise fp32 -> bf16 ----------------
__global__ __launch_bounds__(256) void cvt_bf16(const float* __restrict__ in,
                                                unsigned short* __restrict__ out, int n) {
  int i = (blockIdx.x * 256 + threadIdx.x) * 4;
  if (i < n) {
    float4 v = *(const float4*)(in + i);
    ushort4 o;
    o.x = f2bf(v.x); o.y = f2bf(v.y); o.z = f2bf(v.z); o.w = f2bf(v.w);
    *(ushort4*)(out + i) = o;
  }
}

// ---------------- transpose + convert: out[C][R] = bf16(in[R][C]) ----------------
__global__ __launch_bounds__(256) void transpose_cvt(const float* __restrict__ in,
                                                     unsigned short* __restrict__ out,
                                                     int R, int C) {
  __shared__ float tile[32][33];
  int c0 = blockIdx.x * 32, r0 = blockIdx.y * 32;
  int tx = threadIdx.x & 31, ty = threadIdx.x >> 5; // ty 0..7
  #pragma unroll
  for (int i = 0; i < 32; i += 8)
    tile[ty + i][tx] = in[(size_t)(r0 + ty + i) * C + c0 + tx];
  __syncthreads();
  #pragma unroll
  for (int i = 0; i < 32; i += 8)
    out[(size_t)(c0 + ty + i) * R + r0 + tx] = f2bf(tile[tx][ty + i]);
}

// ---------------- RoPE cos/sin tables [T][32] ----------------
__global__ __launch_bounds__(256) void rope_table(const int* __restrict__ pos,
                                                  float* __restrict__ ctab,
                                                  float* __restrict__ stab) {
  int i = blockIdx.x * 256 + threadIdx.x;  // T*32
  int t = i >> 5, j = i & 31;
  float inv = expf(-(float)j * 0.28782313662425572f);  // 10000^(-j/32)
  float f = (float)pos[t] * inv;
  ctab[i] = cosf(f);
  stab[i] = sinf(f);
}

// ---------------- RoPE apply + split Q,K to [H][T][D] bf16 ----------------
// Q is pre-scaled by 0.125 * log2(e) so softmax runs in exp2 domain.
__global__ __launch_bounds__(256) void rope_split(const float* __restrict__ QKV,
                                                  const float* __restrict__ ctab,
                                                  const float* __restrict__ stab,
                                                  unsigned short* __restrict__ Qh,
                                                  unsigned short* __restrict__ Kh) {
  const float QSCL = 0.18033688011112042f;  // 0.125 * log2e
  int i = blockIdx.x * 256 + threadIdx.x;  // T*NH*32
  int j = i & 31, h = (i >> 5) & 15, t = i >> 9;
  size_t base = (size_t)t * (3 * HID) + h * HD + j;
  float c = ctab[t * 32 + j], s = stab[t * 32 + j];
  float q1 = QKV[base], q2 = QKV[base + 32];
  float k1 = QKV[base + HID], k2 = QKV[base + HID + 32];
  size_t ob = ((size_t)h * T_TOK + t) * HD + j;
  Qh[ob]      = f2bf((q1 * c - q2 * s) * QSCL);
  Qh[ob + 32] = f2bf((q2 * c + q1 * s) * QSCL);
  Kh[ob]      = f2bf(k1 * c - k2 * s);
  Kh[ob + 32] = f2bf(k2 * c + k1 * s);
}

// ---------------- V: QKV[:,2048+h*64+d] -> Vt[H][D][T] bf16 ----------------
__global__ __launch_bounds__(256) void v_transpose(const float* __restrict__ QKV,
                                                   unsigned short* __restrict__ Vt) {
  int h = blockIdx.y;
  int t0 = blockIdx.x * 64;
  __shared__ unsigned short lds[64][72];
  int tx = threadIdx.x & 63, ty = threadIdx.x >> 6;  // ty 0..3
  #pragma unroll
  for (int i = 0; i < 16; ++i) {
    int t = ty * 16 + i;
    lds[tx][t] = f2bf(QKV[(size_t)(t0 + t) * (3 * HID) + 2 * HID + h * HD + tx]);
  }
  __syncthreads();
  #pragma unroll
  for (int i = 0; i < 16; ++i) {
    int d = ty * 16 + i;
    Vt[((size_t)h * HD + d) * T_TOK + t0 + tx] = lds[d][tx];
  }
}

// ---------------- GEMM: C[M,N] f32 = A[M,K] bf16 x Bt[N,K] bf16 ----------------
__global__ __launch_bounds__(256) void gemm_bt(const unsigned short* __restrict__ A,
                                               const unsigned short* __restrict__ Bt,
                                               float* __restrict__ C,
                                               int M, int N, int K) {
  __shared__ unsigned short As[128 * 64];
  __shared__ unsigned short Bs[128 * 64];
  const int lane = threadIdx.x & 63;
  const int wv = threadIdx.x >> 6;
  const int wm = wv >> 1, wn = wv & 1;
  const int r = lane & 15, hi = lane >> 4;
  const int m0 = blockIdx.y * 128, n0 = blockIdx.x * 128;
  f32x4 acc[4][4] = {};
  for (int kt = 0; kt < K; kt += 64) {
    __syncthreads();
    #pragma unroll
    for (int i = 0; i < 4; ++i) {
      int o = (wv * 4 + i) * 1024 + lane * 16;  // byte offset into 16KB tile
      int row = o >> 7;                          // 128B per row (64 bf16)
      int col = (o & 127) >> 1;
      const unsigned short* ga = A + (size_t)(m0 + row) * K + kt + col;
      __builtin_amdgcn_global_load_lds(
          (const __attribute__((address_space(1))) unsigned int*)ga,
          (__attribute__((address_space(3))) unsigned int*)((char*)As + (wv * 4 + i) * 1024),
          16, 0, 0);
      const unsigned short* gb = Bt + (size_t)(n0 + row) * K + kt + col;
      __builtin_amdgcn_global_load_lds(
          (const __attribute__((address_space(1))) unsigned int*)gb,
          (__attribute__((address_space(3))) unsigned int*)((char*)Bs + (wv * 4 + i) * 1024),
          16, 0, 0);
    }
    __syncthreads();
    #pragma unroll
    for (int kk = 0; kk < 2; ++kk) {
      bf16x8 a[4], b[4];
      #pragma unroll
      for (int tm = 0; tm < 4; ++tm)
        a[tm] = *(const bf16x8*)&As[(wm * 64 + tm * 16 + r) * 64 + kk * 32 + hi * 8];
      #pragma unroll
      for (int tn = 0; tn < 4; ++tn)
        b[tn] = *(const bf16x8*)&Bs[(wn * 64 + tn * 16 + r) * 64 + kk * 32 + hi * 8];
      #pragma unroll
      for (int tm = 0; tm < 4; ++tm)
        #pragma unroll
        for (int tn = 0; tn < 4; ++tn)
          acc[tm][tn] = __builtin_amdgcn_mfma_f32_16x16x32_bf16(a[tm], b[tn], acc[tm][tn], 0, 0, 0);
    }
  }
  #pragma unroll
  for (int tm = 0; tm < 4; ++tm)
    #pragma unroll
    for (int tn = 0; tn < 4; ++tn) {
      int colg = n0 + wn * 64 + tn * 16 + r;
      int rowg = m0 + wm * 64 + tm * 16 + hi * 4;
      float* cp = C + (size_t)rowg * N + colg;
      #pragma unroll
      for (int j = 0; j < 4; ++j) cp[(size_t)j * N] = acc[tm][tn][j];
    }
}

// ---------------- flash attention, KV-split, register-P (K=16 PV) ----------------
// grid: 1D T/64 * NH * KVSPLIT, XCD-remapped so all 16 heads of a (qtile,z)
// group are contiguous on one XCD (mask tile L2 reuse).
// block 256 = 4 waves x 16 q-rows. KVBLK=64. LDS = Ks+Vs = 16KB.
__global__ __launch_bounds__(256) void flash_attn(const unsigned short* __restrict__ Qh,
                                                  const unsigned short* __restrict__ Kh,
                                                  const unsigned short* __restrict__ Vt,
                                                  const float* __restrict__ mask,
                                                  float* __restrict__ Op,
                                                  float* __restrict__ Mp,
                                                  float* __restrict__ Lp) {
  const int NBLK = (T_TOK / 64) * NH * KVSPLIT;     // 3072, divisible by 8
  int id = blockIdx.x;
  int sid = (id & 7) * (NBLK / 8) + (id >> 3);      // bijective XCD chunking
  const int h = sid & 15;
  int t2 = sid >> 4;                                 // 0..191
  const int qx = t2 % (T_TOK / 64);
  const int z  = t2 / (T_TOK / 64);
  const int q0 = qx * 64;
  const int kv0 = z * KVCHUNK;

  __shared__ unsigned short Ks[64 * 64];
  __shared__ unsigned short Vs[64 * 64];
  const int lane = threadIdx.x & 63, wv = threadIdx.x >> 6;
  const int r = lane & 15, hi = lane >> 4;
  const int qrow = q0 + wv * 16 + r;
  const bf16x8 qf0 = *(const bf16x8*)(Qh + ((size_t)h * T_TOK + qrow) * HD + hi * 8);
  const bf16x8 qf1 = *(const bf16x8*)(Qh + ((size_t)h * T_TOK + qrow) * HD + 32 + hi * 8);
  f32x4 acc_o[4] = {};
  float m = -INFINITY, l = 0.f;

  // global_load_lds staging: LDS written linearly (base + lane*16), source
  // pre-swizzled so LDS[row][cb] = src[row][cb ^ ((row&7)<<4)].
  const int ldrow = lane >> 3;                         // == dest row & 7
  const int colS  = ((lane & 7) * 16) ^ (ldrow << 4);  // source byte col
  const unsigned short* kga = Kh + ((size_t)h * T_TOK + wv * 16 + ldrow) * HD + (colS >> 1);
  const unsigned short* vga = Vt + ((size_t)h * HD + wv * 16 + ldrow) * T_TOK + (colS >> 1);
  char* ksd = (char*)Ks + wv * 2048;
  char* vsd = (char*)Vs + wv * 2048;
  const float* mrow = mask + (size_t)qrow * T_TOK;

  for (int s0 = kv0; s0 < kv0 + KVCHUNK; s0 += 64) {
    __syncthreads();  // previous tile's LDS reads complete
    __builtin_amdgcn_global_load_lds(
        (const __attribute__((address_space(1))) unsigned int*)(kga + (size_t)s0 * HD),
        (__attribute__((address_space(3))) unsigned int*)ksd, 16, 0, 0);
    __builtin_amdgcn_global_load_lds(
        (const __attribute__((address_space(1))) unsigned int*)(kga + (size_t)s0 * HD + 8 * HD),
        (__attribute__((address_space(3))) unsigned int*)(ksd + 1024), 16, 0, 0);
    __builtin_amdgcn_global_load_lds(
        (const __attribute__((address_space(1))) unsigned int*)(vga + s0),
        (__attribute__((address_space(3))) unsigned int*)vsd, 16, 0, 0);
    __builtin_amdgcn_global_load_lds(
        (const __attribute__((address_space(1))) unsigned int*)(vga + s0 + 8 * T_TOK),
        (__attribute__((address_space(3))) unsigned int*)(vsd + 1024), 16, 0, 0);
    // mask loads issue here; latency hides under the staging drain
    float4 mk[4];
    #pragma unroll
    for (int b = 0; b < 4; ++b) mk[b] = *(const float4*)(mrow + s0 + b * 16 + hi * 4);
    __syncthreads();  // compiler's vmcnt(0) drain -> LDS + mask ready

    // QK^T -> S^T[kv,q]; Q pre-scaled by 0.125*log2e, mask folded via fma
    float sv[16];
    __builtin_amdgcn_s_setprio(1);
    #pragma unroll
    for (int b = 0; b < 4; ++b) {
      bf16x8 kf0 = *(const bf16x8*)&Ks[swz(b * 16 + r, hi * 16)];
      bf16x8 kf1 = *(const bf16x8*)&Ks[swz(b * 16 + r, 64 + hi * 16)];
      f32x4 zf = {};
      zf = __builtin_amdgcn_mfma_f32_16x16x32_bf16(kf0, qf0, zf, 0, 0, 0);
      zf = __builtin_amdgcn_mfma_f32_16x16x32_bf16(kf1, qf1, zf, 0, 0, 0);
      sv[b * 4 + 0] = fmaf(mk[b].x, LOG2E, zf[0]);
      sv[b * 4 + 1] = fmaf(mk[b].y, LOG2E, zf[1]);
      sv[b * 4 + 2] = fmaf(mk[b].z, LOG2E, zf[2]);
      sv[b * 4 + 3] = fmaf(mk[b].w, LOG2E, zf[3]);
    }
    __builtin_amdgcn_s_setprio(0);

    // row max via max3 tree + 4-lane group reduce
    float t0 = fmaxf(fmaxf(sv[0], sv[1]), sv[2]);
    float t1 = fmaxf(fmaxf(sv[3], sv[4]), sv[5]);
    float t2m = fmaxf(fmaxf(sv[6], sv[7]), sv[8]);
    float t3 = fmaxf(fmaxf(sv[9], sv[10]), sv[11]);
    float t4 = fmaxf(fmaxf(sv[12], sv[13]), sv[14]);
    float pmax = fmaxf(fmaxf(fmaxf(t0, t1), t2m), fmaxf(fmaxf(t3, t4), sv[15]));
    pmax = fmaxf(pmax, __shfl_xor(pmax, 16));
    pmax = fmaxf(pmax, __shfl_xor(pmax, 32));

    // defer-max: only rescale when the running max grew by > 8 (log2 units)
    if (__any(pmax > m + 8.f)) {
      float mnew = fmaxf(m, pmax);
      float sc = __builtin_amdgcn_exp2f(m - mnew);
      m = mnew;
      l *= sc;
      float sc0 = __shfl(sc, hi * 4 + 0);
      float sc1 = __shfl(sc, hi * 4 + 1);
      float sc2 = __shfl(sc, hi * 4 + 2);
      float sc3 = __shfl(sc, hi * 4 + 3);
      #pragma unroll
      for (int d = 0; d < 4; ++d) {
        acc_o[d][0] *= sc0; acc_o[d][1] *= sc1;
        acc_o[d][2] *= sc2; acc_o[d][3] *= sc3;
      }
    }

    // P = exp2(sv - m), packed straight into K=16 A-fragments (no LDS roundtrip)
    float ps = 0.f;
    bf16x4 pa[4];
    #pragma unroll
    for (int b = 0; b < 4; ++b) {
      bf16x4 t;
      #pragma unroll
      for (int j = 0; j < 4; ++j) {
        float p = __builtin_amdgcn_exp2f(sv[b * 4 + j] - m);
        ps += p;
        t[j] = (short)f2bf(p);
      }
      pa[b] = t;
    }
    ps += __shfl_xor(ps, 16);
    ps += __shfl_xor(ps, 32);
    l += ps;

    // PV: O[q,d] += P[q,kv] * V[kv,d] via 16 x mfma_16x16x16 (A = pa, in regs)
    __builtin_amdgcn_s_setprio(1);
    #pragma unroll
    for (int d = 0; d < 4; ++d)
      #pragma unroll
      for (int b = 0; b < 4; ++b) {
        bf16x4 vf = *(const bf16x4*)&Vs[swz(d * 16 + r, b * 32 + hi * 8)];
        acc_o[d] = __builtin_amdgcn_mfma_f32_16x16x16bf16_1k(pa[b], vf, acc_o[d], 0, 0, 0);
      }
    __builtin_amdgcn_s_setprio(0);
  }

  // epilogue: write unnormalized partials + (m,l) (m in log2 domain)
  #pragma unroll
  for (int d = 0; d < 4; ++d)
    #pragma unroll
    for (int j = 0; j < 4; ++j) {
      int trow = q0 + wv * 16 + hi * 4 + j;
      Op[(((size_t)z * T_TOK + trow) * NH + h) * HD + d * 16 + r] = acc_o[d][j];
    }
  if (hi == 0) {
    size_t mi = ((size_t)z * T_TOK + qrow) * NH + h;
    Mp[mi] = m;
    Lp[mi] = l;
  }
}

// ---------------- combine KV-split partials (log2-domain maxes) ----------------
__global__ __launch_bounds__(256) void combine(const float* __restrict__ Op,
                                               const float* __restrict__ Mp,
                                               const float* __restrict__ Lp,
                                               unsigned short* __restrict__ Ob) {
  int idx = blockIdx.x * 256 + threadIdx.x;  // T*256 total (4 floats each)
  int t = idx >> 8;
  int q4 = (idx & 255) * 4;  // within [HID): h*64 + d
  int h = q4 >> 6, d = q4 & 63;
  float mz[KVSPLIT], lz[KVSPLIT];
  float ms = -INFINITY;
  #pragma unroll
  for (int zz = 0; zz < KVSPLIT; ++zz) {
    size_t mi = ((size_t)zz * T_TOK + t) * NH + h;
    mz[zz] = Mp[mi];
    lz[zz] = Lp[mi];
    ms = fmaxf(ms, mz[zz]);
  }
  float lsum = 0.f;
  float w[KVSPLIT];
  #pragma unroll
  for (int zz = 0; zz < KVSPLIT; ++zz) {
    w[zz] = __builtin_amdgcn_exp2f(mz[zz] - ms);
    lsum += lz[zz] * w[zz];
  }
  float4 o = {0.f, 0.f, 0.f, 0.f};
  #pragma unroll
  for (int zz = 0; zz < KVSPLIT; ++zz) {
    float4 p = *(const float4*)(Op + (((size_t)zz * T_TOK + t) * NH + h) * HD + d);
    o.x += p.x * w[zz]; o.y += p.y * w[zz];
    o.z += p.z * w[zz]; o.w += p.w * w[zz];
  }
  float inv = 1.f / lsum;
  ushort4 ob;
  ob.x = f2bf(o.x * inv); ob.y = f2bf(o.y * inv);
  ob.z = f2bf(o.z * inv); ob.w = f2bf(o.w * inv);
  *(ushort4*)(Ob + (size_t)t * HID + q4) = ob;
}

extern "C" void kernel_launch(void* const* d_in, const int* in_sizes, int n_in,
                              void* d_out, int out_size, void* d_ws, size_t ws_size,
                              hipStream_t stream) {
  const float* X    = (const float*)d_in[0];
  const float* Wqkv = (const float*)d_in[1];
  const float* Wo   = (const float*)d_in[2];
  const float* mask = (const float*)d_in[3];
  const int*   pos  = (const int*)d_in[4];
  float* out = (float*)d_out;

  char* ws = (char*)d_ws;
  size_t off = 0;
  auto alloc = [&](size_t bytes) {
    char* p = ws + off;
    off += (bytes + 255) & ~(size_t)255;
    return p;
  };
  unsigned short* Xb    = (unsigned short*)alloc((size_t)T_TOK * HID * 2);
  unsigned short* WqkvT = (unsigned short*)alloc((size_t)3 * HID * HID * 2);
  unsigned short* WoT   = (unsigned short*)alloc((size_t)HID * HID * 2);
  unsigned short* Qh    = (unsigned short*)alloc((size_t)NH * T_TOK * HD * 2);
  unsigned short* Kh    = (unsigned short*)alloc((size_t)NH * T_TOK * HD * 2);
  unsigned short* Vt    = (unsigned short*)alloc((size_t)NH * HD * T_TOK * 2);
  unsigned short* Ob    = (unsigned short*)alloc((size_t)T_TOK * HID * 2);
  float*          ctab  = (float*)alloc((size_t)T_TOK * 32 * 4);
  float*          stab  = (float*)alloc((size_t)T_TOK * 32 * 4);
  float*          Mp    = (float*)alloc((size_t)KVSPLIT * T_TOK * NH * 4);
  float*          Lp    = (float*)alloc((size_t)KVSPLIT * T_TOK * NH * 4);
  // REGION: QKV (f32 T x 3H = 37.75MB) aliased with Opart (f32 KVSPLIT x T x HID = 50.3MB).
  // QKV is dead once rope_split + v_transpose complete, before flash_attn writes Op.
  float*          QKV   = (float*)alloc((size_t)KVSPLIT * T_TOK * HID * 4);
  float*          Op    = QKV;

  cvt_bf16<<<(T_TOK * HID / 4 + 255) / 256, 256, 0, stream>>>(X, Xb, T_TOK * HID);
  transpose_cvt<<<dim3(3 * HID / 32, HID / 32), 256, 0, stream>>>(Wqkv, WqkvT, HID, 3 * HID);
  transpose_cvt<<<dim3(HID / 32, HID / 32), 256, 0, stream>>>(Wo, WoT, HID, HID);
  rope_table<<<T_TOK * 32 / 256, 256, 0, stream>>>(pos, ctab, stab);

  gemm_bt<<<dim3(3 * HID / 128, T_TOK / 128), 256, 0, stream>>>(Xb, WqkvT, QKV, T_TOK, 3 * HID, HID);

  rope_split<<<T_TOK * NH * 32 / 256, 256, 0, stream>>>(QKV, ctab, stab, Qh, Kh);
  v_transpose<<<dim3(T_TOK / 64, NH), 256, 0, stream>>>(QKV, Vt);

  flash_attn<<<dim3((T_TOK / 64) * NH * KVSPLIT), 256, 0, stream>>>(Qh, Kh, Vt, mask, Op, Mp, Lp);
  combine<<<T_TOK, 256, 0, stream>>>(Op, Mp, Lp, Ob);

  gemm_bt<<<dim3(HID / 128, T_TOK / 128), 256, 0, stream>>>(Ob, WoT, out, T_TOK, HID, HID);
}